// Round 10
// baseline (157.175 us; speedup 1.0000x reference)
//
#include <hip/hip_runtime.h>

#define S_    2048
#define N_    16
#define OBS_  8
#define PRED_ 12
#define B_    (S_*N_)
#define SCN_  2     // scenes (waves) per block

typedef __attribute__((ext_vector_type(8))) short short8;
typedef __attribute__((ext_vector_type(4))) float floatx4;
typedef __attribute__((ext_vector_type(4))) unsigned uintx4;
typedef unsigned short ushort_t;

__device__ __forceinline__ float sigmf(float x) { return __builtin_amdgcn_rcpf(1.0f + __expf(-x)); }
__device__ __forceinline__ float tanhx(float x) { return fmaf(-2.0f, __builtin_amdgcn_rcpf(1.0f + __expf(2.0f*x)), 1.0f); }
// f32 -> bf16 round-half-up: bits+0x8000, truncate. <=0.5 ulp like RNE (ties differ only).
__device__ __forceinline__ unsigned bfhi(float f) {
  return __builtin_bit_cast(unsigned, f) + 0x8000u;
}
__device__ __forceinline__ unsigned pack2bf(float lo, float hi) {
  return __builtin_amdgcn_perm(bfhi(hi), bfhi(lo), 0x07060302);  // [hi.b3,hi.b2,lo.b3,lo.b2]
}
__device__ __forceinline__ ushort_t f2bf1(float f) { return (ushort_t)(bfhi(f) >> 16); }
__device__ __forceinline__ float rlanef(float v, int lane) {
  return __builtin_bit_cast(float, __builtin_amdgcn_readlane(__builtin_bit_cast(int, v), lane));
}
__device__ __forceinline__ unsigned shflu(unsigned v, int src) {
  return (unsigned)__shfl((int)v, src, 64);
}
__device__ __forceinline__ unsigned shflxu(unsigned v, int m) {
  return (unsigned)__shfl_xor((int)v, m, 64);
}

// R23 = R22 + phase-5-as-MFMA (FIRST deliberate numerics spend; budget
// 0.106875, measured 0.03125 for 9 rounds). R19/R22 both neutral -> bit-exact
// space exhausted at 70.7us; plateau is mixed issue+latency, no pipe at
// roofline. This round: o4 = (h+ctx)@oW + ob as ONE 16x16x32 MFMA:
//   B-operand = (lq<2 ? cvN : hf)  — EXACT gate-MFMA structure; cvN (bf16 ctx,
//     post-pool load, R22) and hf (bf16 h fragment) are already live regs.
//   A-operand = oW cols on rows 0..3 (one-time, mirrors LOAD_GATE_FRAG kk map).
//   D (m89 layout): lane (lq=0,lc) gets ALL FOUR o4 outputs for agent lc in
//     d[0..3] -> no sc shuffle; float2 stores; prx/pry = 2 shfls from lane lc.
// DELETED: h_s + ctx_s LDS buffers, their writes (1xb128 + 16xb32/step) and
// reads (8xb128/lane/step), and the 32-fma f32 dot — the last LDS RTs on the
// spine. Numerics: o4 sums the SAME bf16 h/ctx the gates/pool already use,
// in MFMA order; expected absmax 0.03-0.08. REVERT RULE: absmax > 0.106875
// -> restore f32 phase 5. Encoder/phase1/2/pool bit-identical to R22.
extern "C" __global__ __launch_bounds__(128, 2) void traj_ar_kernel(
    const float* __restrict__ traj_rel, const float* __restrict__ obs_pos,
    const int*  __restrict__ nei,       const float* __restrict__ noise,
    const float* __restrict__ eeW, const float* __restrict__ eeb,
    const float* __restrict__ eWi, const float* __restrict__ eWh, const float* __restrict__ eb,
    const float* __restrict__ diW, const float* __restrict__ dib,
    const float* __restrict__ dWi, const float* __restrict__ dWh, const float* __restrict__ db,
    const float* __restrict__ prW, const float* __restrict__ prb,
    const float* __restrict__ mW,  const float* __restrict__ mb,
    const float* __restrict__ oW,  const float* __restrict__ ob,
    float* __restrict__ out)
{
  // per-scene (wave-private) state only — nothing cross-wave
  __shared__ __align__(16) ushort_t ctx_bf[SCN_][384]; // bf16 ctx: phase-1 B + phase-5 B
  __shared__            unsigned sm_s[SCN_][16];

  const int tid = threadIdx.x;
  const int w  = tid >> 6;              // wave index == scene-within-block
  const int l  = tid & 63;
  const int lq = l >> 4;                // quad within wave
  const int lc = l & 15;                // col within wave (agent / unit-col)
  const int u0 = lq*4;                  // this lane's unit base
  const int s  = blockIdx.x*SCN_ + w;   // this wave's scene
  const bool hi_half = (lq >= 2);       // lanes 32..63
  // fragment-routing source lanes (R19-proven): lane's b128 e/h fragment =
  // {ep.x,ep.y} of lane esrc0 then lane esrc1
  const int esrc0 = (lq & 1)*32 + lc;
  const int esrc1 = esrc0 + 16;

  // ---- per-wave scene init (no barriers anywhere) ----
  {
    // ctx0 = 0 (FULL 192 uints — R13 lesson); h0 handled by hf=0 below
    unsigned* cz = (unsigned*)ctx_bf[w];
    cz[l] = 0; cz[64+l] = 0; cz[128+l] = 0;
  }
  // pos + prev live in REGISTERS
  float POSX = obs_pos[((OBS_-1)*B_ + s*N_ + lc)*2 + 0];
  float POSY = obs_pos[((OBS_-1)*B_ + s*N_ + lc)*2 + 1];
  unsigned prevu;
  {
    float pvx = traj_rel[((OBS_-1)*B_ + s*N_ + lc)*2 + 0];
    float pvy = traj_rel[((OBS_-1)*B_ + s*N_ + lc)*2 + 1];
    prevu = pack2bf(pvx, pvy);          // [y_bf | x_bf]
  }
  // time-invariant neighbor mask -> per-agent bitmask (wave-private)
  {
    const int a = l >> 2, nb = (l & 3)*4;
    const int4 nv = *(const int4*)&nei[(s*N_ + a)*N_ + nb];
    unsigned bits = 0;
    bits |= (nv.x > 0) ? (1u << (nb+0)) : 0u;
    bits |= (nv.y > 0) ? (1u << (nb+1)) : 0u;
    bits |= (nv.z > 0) ? (1u << (nb+2)) : 0u;
    bits |= (nv.w > 0) ? (1u << (nb+3)) : 0u;
    bits |= __shfl_xor(bits, 1, 64);
    bits |= __shfl_xor(bits, 2, 64);
    if ((l & 3) == 0) sm_s[w][a] = bits;
  }

  // pool-MLP B-fragment (32x16 bf16 weights)
  short8 bfrag;
  {
    uintx4 bw;
    #pragma unroll
    for (int p = 0; p < 4; ++p)
      bw[p] = pack2bf(mW[(8*lq + 2*p)*16 + lc], mW[(8*lq + 2*p + 1)*16 + lc]);
    bfrag = __builtin_bit_cast(short8, bw);
  }
  const float bm = mb[lc];

  // pool-rel weights for this lane's unit octet (lq&1)*8..+7
  float pWx[8], pWy[8], pB[8];
  {
    const int wu0 = (lq & 1) * 8;
    #pragma unroll
    for (int j = 0; j < 8; ++j) {
      pWx[j] = prW[wu0 + j];
      pWy[j] = prW[16 + wu0 + j];
      pB[j]  = prb[wu0 + j];
    }
  }

  // R23: out-layer A-fragment. D[outidx][agent] = Sum_kk A[outidx][kk]*B[kk][agent];
  // kk<16 = ctx rows, kk>=16 = h rows, both hit oW[kk&15]. A-fragment layout:
  // lane (lq,lc) holds A[row=lc][kk = lq*8+j] -> value oW[(lq&1)*8+j][lc], lc<4.
  // C: bias on D-rows lq*4+r -> ob[r] for lq==0, else 0.
  short8 oA; floatx4 oC;
  {
    uintx4 aw; aw[0]=0; aw[1]=0; aw[2]=0; aw[3]=0;
    if (lc < 4) {
      #pragma unroll
      for (int p = 0; p < 4; ++p)
        aw[p] = pack2bf(oW[((lq&1)*8 + 2*p)*4 + lc], oW[((lq&1)*8 + 2*p + 1)*4 + lc]);
    }
    oA = __builtin_bit_cast(short8, aw);
    #pragma unroll
    for (int r = 0; r < 4; ++r) oC[r] = (lq == 0) ? ob[r] : 0.0f;
  }

  // encoder embed weights for this lane's 4 units
  float ew0[4], ew1[4], ebv[4];
  #pragma unroll
  for (int r = 0; r < 4; ++r) {
    ew0[r] = eeW[u0+r]; ew1[r] = eeW[16+u0+r]; ebv[r] = eeb[u0+r];
  }

  const int row0 = (lq & 1) * 8;

  // gate A-fragment for gate g (A[row=lc][k] = W[k][g*16+lc]) + bias C by D-row unit
  #define LOAD_GATE_FRAG(A, C, Wi_, Wh_, bias_, g) {                                      \
    const float* gsrc_ = (lq & 2) ? (Wh_) : (Wi_);                                        \
    uintx4 aw_;                                                                           \
    aw_[0] = pack2bf(gsrc_[(row0+0)*64 + (g)*16 + lc], gsrc_[(row0+1)*64 + (g)*16 + lc]); \
    aw_[1] = pack2bf(gsrc_[(row0+2)*64 + (g)*16 + lc], gsrc_[(row0+3)*64 + (g)*16 + lc]); \
    aw_[2] = pack2bf(gsrc_[(row0+4)*64 + (g)*16 + lc], gsrc_[(row0+5)*64 + (g)*16 + lc]); \
    aw_[3] = pack2bf(gsrc_[(row0+6)*64 + (g)*16 + lc], gsrc_[(row0+7)*64 + (g)*16 + lc]); \
    (A) = __builtin_bit_cast(short8, aw_);                                                \
    (C)[0] = (bias_)[(g)*16 + u0 + 0]; (C)[1] = (bias_)[(g)*16 + u0 + 1];                 \
    (C)[2] = (bias_)[(g)*16 + u0 + 2]; (C)[3] = (bias_)[(g)*16 + u0 + 3];                 \
  }

  // encoder gate A-frags, all 4 gates on this wave
  short8 eA0, eA1, eA2, eA3; floatx4 eC0, eC1, eC2, eC3;
  LOAD_GATE_FRAG(eA0, eC0, eWi, eWh, eb, 0);
  LOAD_GATE_FRAG(eA1, eC1, eWi, eWh, eb, 1);
  LOAD_GATE_FRAG(eA2, eC2, eWi, eWh, eb, 2);
  LOAD_GATE_FRAG(eA3, eC3, eWi, eWh, eb, 3);

  #define LSTM_EW(r, hv) {                                                            \
    float ig = sigmf(dI[r]), fg = sigmf(dF[r]), gv = tanhx(dG[r]), og = sigmf(dO[r]); \
    c4[r] = fg*c4[r] + ig*gv;                                                         \
    hv = og * tanhx(c4[r]);                                                           \
  }

  // h fragment (B-operand rows (lq&1)*8..+8 of agent lc), carried across steps.
  uintx4 hf; hf[0]=0; hf[1]=0; hf[2]=0; hf[3]=0;

  // ---- encoder: 8 LSTM steps, zero barriers, zero LDS (regs + shfl only) ----
  floatx4 c4 = {0.0f, 0.0f, 0.0f, 0.0f};
  const float2* xr2 = (const float2*)traj_rel;
  for (int t = 0; t < OBS_; ++t) {
    float2 x = xr2[t*B_ + s*N_ + lc];
    float e0 = fmaxf(fmaf(x.y, ew1[0], fmaf(x.x, ew0[0], ebv[0])), 0.0f);
    float e1 = fmaxf(fmaf(x.y, ew1[1], fmaf(x.x, ew0[1], ebv[1])), 0.0f);
    float e2 = fmaxf(fmaf(x.y, ew1[2], fmaf(x.x, ew0[2], ebv[2])), 0.0f);
    float e3 = fmaxf(fmaf(x.y, ew1[3], fmaf(x.x, ew0[3], ebv[3])), 0.0f);
    uint2 ep; ep.x = pack2bf(e0, e1); ep.y = pack2bf(e2, e3);
    uintx4 eu;
    eu[0] = shflu(ep.x, esrc0); eu[1] = shflu(ep.y, esrc0);
    eu[2] = shflu(ep.x, esrc1); eu[3] = shflu(ep.y, esrc1);
    uintx4 bu = (lq < 2) ? eu : hf;     // hi lanes: h of PREVIOUS step
    short8 bfr = __builtin_bit_cast(short8, bu);
    floatx4 dI = __builtin_amdgcn_mfma_f32_16x16x32_bf16(eA0, bfr, eC0, 0, 0, 0);
    floatx4 dF = __builtin_amdgcn_mfma_f32_16x16x32_bf16(eA1, bfr, eC1, 0, 0, 0);
    floatx4 dG = __builtin_amdgcn_mfma_f32_16x16x32_bf16(eA2, bfr, eC2, 0, 0, 0);
    floatx4 dO = __builtin_amdgcn_mfma_f32_16x16x32_bf16(eA3, bfr, eC3, 0, 0, 0);
    float h40, h41, h42, h43;
    LSTM_EW(0, h40); LSTM_EW(1, h41); LSTM_EW(2, h42); LSTM_EW(3, h43);
    uint2 hp2; hp2.x = pack2bf(h40, h41); hp2.y = pack2bf(h42, h43);
    hf[0] = shflu(hp2.x, esrc0); hf[1] = shflu(hp2.y, esrc0);
    hf[2] = shflu(hp2.x, esrc1); hf[3] = shflu(hp2.y, esrc1);
  }

  // decoder gate A-frags (separate live range from encoder's)
  short8 dA0, dA1, dA2, dA3; floatx4 dC0, dC1, dC2, dC3;
  LOAD_GATE_FRAG(dA0, dC0, dWi, dWh, db, 0);
  LOAD_GATE_FRAG(dA1, dC1, dWi, dWh, db, 1);
  LOAD_GATE_FRAG(dA2, dC2, dWi, dWh, db, 2);
  LOAD_GATE_FRAG(dA3, dC3, dWi, dWh, db, 3);

  // dec-in A-fragment: kk 0..15 = ctx rows, 16,17 = prev rows, 18..31 zero-pad
  short8 diA; floatx4 diC;
  {
    uintx4 aw; aw[0]=0; aw[1]=0; aw[2]=0; aw[3]=0;
    if (lq < 2) {
      const int r0 = lq*8;
      #pragma unroll
      for (int p = 0; p < 4; ++p)
        aw[p] = pack2bf(diW[(r0+2*p)*16 + lc], diW[(r0+2*p+1)*16 + lc]);
    } else if (lq == 2) {
      aw[0] = pack2bf(diW[16*16 + lc], diW[17*16 + lc]);
    }
    diA = __builtin_bit_cast(short8, aw);
    #pragma unroll
    for (int r = 0; r < 4; ++r) diC[r] = dib[u0 + r];
  }

  // pool C-operands, all 16 target agents, mask baked (time-invariant).
  floatx4 cm[16];
  #pragma unroll
  for (int tt = 0; tt < 16; ++tt) {
    const unsigned mi = sm_s[w][tt];
    #pragma unroll
    for (int r = 0; r < 4; ++r)
      cm[tt][r] = ((mi >> (u0 + r)) & 1u) ? bm : -1e9f;
  }

  // R19-identical refrag: lanes<32 re(2pp), lanes>=32 re(2pp+1); F1 routed
  // down via proven shfl_xor(32). Bit-identical fma nesting + pack pairing.
  #define MK_REFRAG(pp, F0, F1) {                                           \
    const int t0_ = 2*(pp), t1_ = 2*(pp)+1;                                 \
    float rx0_ = PXs[t0_] - POSX, ry0_ = PYs[t0_] - POSY;                   \
    float rx1_ = PXs[t1_] - POSX, ry1_ = PYs[t1_] - POSY;                   \
    float rx_ = hi_half ? rx1_ : rx0_;                                      \
    float ry_ = hi_half ? ry1_ : ry0_;                                      \
    float rr_[8];                                                           \
    _Pragma("unroll")                                                       \
    for (int j = 0; j < 8; ++j)                                             \
      rr_[j] = fmaxf(fmaf(ry_, pWy[j], fmaf(rx_, pWx[j], pB[j])), 0.0f);    \
    (F0)[0] = pack2bf(rr_[0], rr_[1]);                                      \
    (F0)[1] = pack2bf(rr_[2], rr_[3]);                                      \
    (F0)[2] = pack2bf(rr_[4], rr_[5]);                                      \
    (F0)[3] = pack2bf(rr_[6], rr_[7]);                                      \
    (F1)[0] = shflxu((F0)[0], 32);                                          \
    (F1)[1] = shflxu((F0)[1], 32);                                          \
    (F1)[2] = shflxu((F0)[2], 32);                                          \
    (F1)[3] = shflxu((F0)[3], 32);                                          \
  }

  // pool tile (R22-identical minus the ctx_s f32 write)
  #define POOL_TILE(tt, FRAG) {                                             \
    short8 a_ = hi_half ? __builtin_bit_cast(short8, hf)                    \
                        : __builtin_bit_cast(short8, FRAG);                 \
    floatx4 d_ = __builtin_amdgcn_mfma_f32_16x16x32_bf16(a_, bfrag, cm[tt], 0, 0, 0); \
    float pm_ = fmaxf(fmaxf(d_[0], d_[1]), fmaxf(d_[2], d_[3]));            \
    pm_ = fmaxf(pm_, __shfl_xor(pm_, 16, 64));                              \
    pm_ = fmaxf(pm_, __shfl_xor(pm_, 32, 64));                              \
    if (lq == ((tt) & 3)) {                                                 \
      ctx_bf[w][(tt)*24 + lc] = f2bf1(fmaxf(pm_, 0.0f));                    \
    }                                                                       \
  }

  // ---- decoder: 12 autoregressive steps, ZERO barriers ----
  c4 = (floatx4){0.0f, 0.0f, 0.0f, 0.0f};
  const int MU_OFF = PRED_*B_*2;
  const int SD_OFF = 2*PRED_*B_*2;
  const float2* nz2p = (const float2*)noise;
  // prologue ctx load (step-0 ctx = zeros, written above by THIS wave)
  short8 cvN = *(const short8*)&ctx_bf[w][lc*24 + (lq&1)*8];
  for (int t = 0; t < PRED_; ++t) {
    // early noise load (float2; consumed in phase 5 by lq==0 lanes)
    const float2 nz2 = nz2p[t*B_ + s*N_ + lc];
    // phase 0: all-agent pos snapshot -> uniform regs (32 v_readlane)
    float PXs[16], PYs[16];
    #pragma unroll
    for (int a2 = 0; a2 < 16; ++a2) {
      PXs[a2] = rlanef(POSX, a2);
      PYs[a2] = rlanef(POSY, a2);
    }
    // pair-0 re fragments hoisted: their shuffles overlap phases 1-2
    uintx4 g0, g1;
    MK_REFRAG(0, g0, g1);
    // phase 1: e = relu([ctx|prev] @ dec_in_W + b) via MFMA (ctx from cvN)
    uint2 ep;
    {
      uintx4 pz; pz[0] = prevu; pz[1]=0; pz[2]=0; pz[3]=0;
      short8 pv = __builtin_bit_cast(short8, pz);
      short8 zz = {0,0,0,0,0,0,0,0};
      short8 bf1 = (lq < 2) ? cvN : ((lq == 2) ? pv : zz);
      __builtin_amdgcn_s_setprio(1);
      floatx4 d = __builtin_amdgcn_mfma_f32_16x16x32_bf16(diA, bf1, diC, 0, 0, 0);
      __builtin_amdgcn_s_setprio(0);
      ep.x = pack2bf(fmaxf(d[0],0.0f), fmaxf(d[1],0.0f));
      ep.y = pack2bf(fmaxf(d[2],0.0f), fmaxf(d[3],0.0f));
    }
    // phase 2: e fragment via 4 shfl; 4 gate MFMAs + elementwise; h -> hf only
    {
      uintx4 eu;
      eu[0] = shflu(ep.x, esrc0); eu[1] = shflu(ep.y, esrc0);
      eu[2] = shflu(ep.x, esrc1); eu[3] = shflu(ep.y, esrc1);
      uintx4 bu = (lq < 2) ? eu : hf;   // hi lanes: h of PREVIOUS step
      short8 bfr = __builtin_bit_cast(short8, bu);
      __builtin_amdgcn_s_setprio(1);
      floatx4 dI = __builtin_amdgcn_mfma_f32_16x16x32_bf16(dA0, bfr, dC0, 0, 0, 0);
      floatx4 dF = __builtin_amdgcn_mfma_f32_16x16x32_bf16(dA1, bfr, dC1, 0, 0, 0);
      floatx4 dG = __builtin_amdgcn_mfma_f32_16x16x32_bf16(dA2, bfr, dC2, 0, 0, 0);
      floatx4 dO = __builtin_amdgcn_mfma_f32_16x16x32_bf16(dA3, bfr, dC3, 0, 0, 0);
      __builtin_amdgcn_s_setprio(0);
      float h40, h41, h42, h43;
      LSTM_EW(0, h40); LSTM_EW(1, h41); LSTM_EW(2, h42); LSTM_EW(3, h43);
      uint2 hp2; hp2.x = pack2bf(h40, h41); hp2.y = pack2bf(h42, h43);
      hf[0] = shflu(hp2.x, esrc0); hf[1] = shflu(hp2.y, esrc0);
      hf[2] = shflu(hp2.x, esrc1); hf[3] = shflu(hp2.y, esrc1);
    }
    // phase 4: masked max-pool, 8 tile-pairs, lookahead-1 pipeline
    {
      #pragma unroll
      for (int p = 0; p < 8; ++p) {
        uintx4 n0, n1;
        if (p < 7) MK_REFRAG(p+1, n0, n1);
        POOL_TILE(2*p,     g0);
        POOL_TILE(2*p + 1, g1);
        g0 = n0; g1 = n1;
      }
    }
    // reload ctx fragment: this step's ctx (phase-5 B operand) AND next
    // step's phase-1 input (same-wave in-order LDS after pool writes)
    cvN = *(const short8*)&ctx_bf[w][lc*24 + (lq&1)*8];
    // phase 5 (R23): o4 via ONE MFMA. D[outidx=lq*4+r][agent=lc]:
    // lane (0,lc) holds {mu_x, mu_y, scale_x, scale_y} for agent lc.
    {
      uintx4 bu = (lq < 2) ? __builtin_bit_cast(uintx4, cvN) : hf;
      short8 bfr = __builtin_bit_cast(short8, bu);
      floatx4 d = __builtin_amdgcn_mfma_f32_16x16x32_bf16(oA, bfr, oC, 0, 0, 0);
      float mux = d[0], muy = d[1];
      float scx = fminf(fmaxf(d[2], -9.0f), 4.0f);
      float scy = fminf(fmaxf(d[3], -9.0f), 4.0f);
      float sdx = __expf(scx);
      float sdy = __expf(scy);
      float prxv = fmaf(sdx, nz2.x, mux);
      float pryv = fmaf(sdy, nz2.y, muy);
      if (lq == 0) {
        int o = (t*B_ + s*N_ + lc)*2;
        float2 v0; v0.x = prxv; v0.y = pryv;
        float2 v1; v1.x = mux;  v1.y = muy;
        float2 v2; v2.x = sdx;  v2.y = sdy;
        *(float2*)&out[o]          = v0;
        *(float2*)&out[MU_OFF + o] = v1;
        *(float2*)&out[SD_OFF + o] = v2;
      }
      float prx = __shfl(prxv, lc, 64);    // agent lc's x-delta (lane (0,lc))
      float pry = __shfl(pryv, lc, 64);    // agent lc's y-delta (same lane)
      POSX += prx;
      POSY += pry;
      prevu = pack2bf(prx, pry);
    }
  }
  #undef LSTM_EW
  #undef LOAD_GATE_FRAG
  #undef MK_REFRAG
  #undef POOL_TILE
}

extern "C" void kernel_launch(void* const* d_in, const int* in_sizes, int n_in,
                              void* d_out, int out_size, void* d_ws, size_t ws_size,
                              hipStream_t stream) {
  (void)in_sizes; (void)n_in; (void)d_ws; (void)ws_size; (void)out_size;
  traj_ar_kernel<<<dim3(S_/SCN_), dim3(128), 0, stream>>>(
      (const float*)d_in[0],  (const float*)d_in[1],  (const int*)d_in[2],   (const float*)d_in[3],
      (const float*)d_in[4],  (const float*)d_in[5],  (const float*)d_in[6], (const float*)d_in[7],
      (const float*)d_in[8],  (const float*)d_in[9],  (const float*)d_in[10],(const float*)d_in[11],
      (const float*)d_in[12], (const float*)d_in[13], (const float*)d_in[14],(const float*)d_in[15],
      (const float*)d_in[16], (const float*)d_in[17], (const float*)d_in[18],(const float*)d_in[19],
      (float*)d_out);
}

// Round 11
// 155.414 us; speedup vs baseline: 1.0113x; 1.0113x over previous
//
#include <hip/hip_runtime.h>

#define S_    2048
#define N_    16
#define OBS_  8
#define PRED_ 12
#define B_    (S_*N_)
#define SCN_  2     // scenes (waves) per block

typedef __attribute__((ext_vector_type(8))) short short8;
typedef __attribute__((ext_vector_type(4))) float floatx4;
typedef __attribute__((ext_vector_type(2))) float floatx2;
typedef __attribute__((ext_vector_type(4))) unsigned uintx4;
typedef unsigned short ushort_t;

// Packed f32 math (v_pk_fma_f32 / v_pk_max_f32): per-element rounding is
// IDENTICAL to scalar fmaf/fmaxf -> bit-exact. Guarded: scalar fallback.
#if __has_builtin(__builtin_elementwise_fma) && __has_builtin(__builtin_elementwise_max)
#define HAVE_PK 1
#define FMA2(a,b,c) __builtin_elementwise_fma((a),(b),(c))
#define MAX2(a,b)   __builtin_elementwise_max((a),(b))
#else
#define HAVE_PK 0
#endif

__device__ __forceinline__ float sigmf(float x) { return __builtin_amdgcn_rcpf(1.0f + __expf(-x)); }
__device__ __forceinline__ float tanhx(float x) { return fmaf(-2.0f, __builtin_amdgcn_rcpf(1.0f + __expf(2.0f*x)), 1.0f); }
// f32 -> bf16 round-half-up: bits+0x8000, truncate. <=0.5 ulp like RNE (ties differ only).
__device__ __forceinline__ unsigned bfhi(float f) {
  return __builtin_bit_cast(unsigned, f) + 0x8000u;
}
__device__ __forceinline__ unsigned pack2bf(float lo, float hi) {
  return __builtin_amdgcn_perm(bfhi(hi), bfhi(lo), 0x07060302);  // [hi.b3,hi.b2,lo.b3,lo.b2]
}
__device__ __forceinline__ ushort_t f2bf1(float f) { return (ushort_t)(bfhi(f) >> 16); }
__device__ __forceinline__ float rlanef(float v, int lane) {
  return __builtin_bit_cast(float, __builtin_amdgcn_readlane(__builtin_bit_cast(int, v), lane));
}
__device__ __forceinline__ unsigned shflu(unsigned v, int src) {
  return (unsigned)__shfl((int)v, src, 64);
}
__device__ __forceinline__ unsigned shflxu(unsigned v, int m) {
  return (unsigned)__shfl_xor((int)v, m, 64);
}

// R24 = R23 (66.5us, absmax 0.03125) + packed-f32 issue cuts, ALL bit-exact.
// R23 post-mortem: phase5-MFMA matched (-6%, conflicts 3.7M->762K); regime is
// issue+latency mix (VALU 55%, no pipe near roofline). Largest issue block =
// MK_REFRAG (~192 fma/max + 96 pack ops/step). This round:
//  1. refrag inner loop via v_pk_fma_f32/v_pk_max_f32 (__builtin_elementwise_*,
//     __has_builtin-guarded, scalar fallback): 24 -> 12 ops/pair, -96 ops/step.
//     Per-element rounding identical to scalar fmaf/fmaxf -> BIT-EXACT.
//  2. pool reduce d[0..3] as nested fmaxf chain -> v_max3_f32 + max (T17);
//     max is associative -> bit-exact. -16 ops/step.
// No routing changes, no new lane-move instructions (R17/R20 lesson).
// absmax MUST stay exactly 0.03125 (tripwire; else transcription bug).
// Tripwires: VGPR > 240 / FETCH-WRITE balloon -> spill -> revert.
extern "C" __global__ __launch_bounds__(128, 2) void traj_ar_kernel(
    const float* __restrict__ traj_rel, const float* __restrict__ obs_pos,
    const int*  __restrict__ nei,       const float* __restrict__ noise,
    const float* __restrict__ eeW, const float* __restrict__ eeb,
    const float* __restrict__ eWi, const float* __restrict__ eWh, const float* __restrict__ eb,
    const float* __restrict__ diW, const float* __restrict__ dib,
    const float* __restrict__ dWi, const float* __restrict__ dWh, const float* __restrict__ db,
    const float* __restrict__ prW, const float* __restrict__ prb,
    const float* __restrict__ mW,  const float* __restrict__ mb,
    const float* __restrict__ oW,  const float* __restrict__ ob,
    float* __restrict__ out)
{
  // per-scene (wave-private) state only — nothing cross-wave
  __shared__ __align__(16) ushort_t ctx_bf[SCN_][384]; // bf16 ctx: phase-1 B + phase-5 B
  __shared__            unsigned sm_s[SCN_][16];

  const int tid = threadIdx.x;
  const int w  = tid >> 6;              // wave index == scene-within-block
  const int l  = tid & 63;
  const int lq = l >> 4;                // quad within wave
  const int lc = l & 15;                // col within wave (agent / unit-col)
  const int u0 = lq*4;                  // this lane's unit base
  const int s  = blockIdx.x*SCN_ + w;   // this wave's scene
  const bool hi_half = (lq >= 2);       // lanes 32..63
  // fragment-routing source lanes (R19-proven): lane's b128 e/h fragment =
  // {ep.x,ep.y} of lane esrc0 then lane esrc1
  const int esrc0 = (lq & 1)*32 + lc;
  const int esrc1 = esrc0 + 16;

  // ---- per-wave scene init (no barriers anywhere) ----
  {
    // ctx0 = 0 (FULL 192 uints — R13 lesson); h0 handled by hf=0 below
    unsigned* cz = (unsigned*)ctx_bf[w];
    cz[l] = 0; cz[64+l] = 0; cz[128+l] = 0;
  }
  // pos + prev live in REGISTERS
  float POSX = obs_pos[((OBS_-1)*B_ + s*N_ + lc)*2 + 0];
  float POSY = obs_pos[((OBS_-1)*B_ + s*N_ + lc)*2 + 1];
  unsigned prevu;
  {
    float pvx = traj_rel[((OBS_-1)*B_ + s*N_ + lc)*2 + 0];
    float pvy = traj_rel[((OBS_-1)*B_ + s*N_ + lc)*2 + 1];
    prevu = pack2bf(pvx, pvy);          // [y_bf | x_bf]
  }
  // time-invariant neighbor mask -> per-agent bitmask (wave-private)
  {
    const int a = l >> 2, nb = (l & 3)*4;
    const int4 nv = *(const int4*)&nei[(s*N_ + a)*N_ + nb];
    unsigned bits = 0;
    bits |= (nv.x > 0) ? (1u << (nb+0)) : 0u;
    bits |= (nv.y > 0) ? (1u << (nb+1)) : 0u;
    bits |= (nv.z > 0) ? (1u << (nb+2)) : 0u;
    bits |= (nv.w > 0) ? (1u << (nb+3)) : 0u;
    bits |= __shfl_xor(bits, 1, 64);
    bits |= __shfl_xor(bits, 2, 64);
    if ((l & 3) == 0) sm_s[w][a] = bits;
  }

  // pool-MLP B-fragment (32x16 bf16 weights)
  short8 bfrag;
  {
    uintx4 bw;
    #pragma unroll
    for (int p = 0; p < 4; ++p)
      bw[p] = pack2bf(mW[(8*lq + 2*p)*16 + lc], mW[(8*lq + 2*p + 1)*16 + lc]);
    bfrag = __builtin_bit_cast(short8, bw);
  }
  const float bm = mb[lc];

  // pool-rel weights for this lane's unit octet (lq&1)*8..+7, packed in pairs
#if HAVE_PK
  floatx2 pWx2[4], pWy2[4], pB2[4];
  {
    const int wu0 = (lq & 1) * 8;
    #pragma unroll
    for (int jj = 0; jj < 4; ++jj) {
      pWx2[jj] = (floatx2){prW[wu0 + 2*jj],      prW[wu0 + 2*jj + 1]};
      pWy2[jj] = (floatx2){prW[16 + wu0 + 2*jj], prW[16 + wu0 + 2*jj + 1]};
      pB2[jj]  = (floatx2){prb[wu0 + 2*jj],      prb[wu0 + 2*jj + 1]};
    }
  }
#else
  float pWx[8], pWy[8], pB[8];
  {
    const int wu0 = (lq & 1) * 8;
    #pragma unroll
    for (int j = 0; j < 8; ++j) {
      pWx[j] = prW[wu0 + j];
      pWy[j] = prW[16 + wu0 + j];
      pB[j]  = prb[wu0 + j];
    }
  }
#endif

  // R23: out-layer A-fragment. D[outidx][agent]; kk<16 = ctx rows, kk>=16 = h
  // rows, both hit oW[kk&15]. Lane (lq,lc): A[row=lc][kk=lq*8+j], lc<4.
  // C: bias on D-rows 0..3 (lq==0), else 0.
  short8 oA; floatx4 oC;
  {
    uintx4 aw; aw[0]=0; aw[1]=0; aw[2]=0; aw[3]=0;
    if (lc < 4) {
      #pragma unroll
      for (int p = 0; p < 4; ++p)
        aw[p] = pack2bf(oW[((lq&1)*8 + 2*p)*4 + lc], oW[((lq&1)*8 + 2*p + 1)*4 + lc]);
    }
    oA = __builtin_bit_cast(short8, aw);
    #pragma unroll
    for (int r = 0; r < 4; ++r) oC[r] = (lq == 0) ? ob[r] : 0.0f;
  }

  // encoder embed weights for this lane's 4 units
  float ew0[4], ew1[4], ebv[4];
  #pragma unroll
  for (int r = 0; r < 4; ++r) {
    ew0[r] = eeW[u0+r]; ew1[r] = eeW[16+u0+r]; ebv[r] = eeb[u0+r];
  }

  const int row0 = (lq & 1) * 8;

  // gate A-fragment for gate g (A[row=lc][k] = W[k][g*16+lc]) + bias C by D-row unit
  #define LOAD_GATE_FRAG(A, C, Wi_, Wh_, bias_, g) {                                      \
    const float* gsrc_ = (lq & 2) ? (Wh_) : (Wi_);                                        \
    uintx4 aw_;                                                                           \
    aw_[0] = pack2bf(gsrc_[(row0+0)*64 + (g)*16 + lc], gsrc_[(row0+1)*64 + (g)*16 + lc]); \
    aw_[1] = pack2bf(gsrc_[(row0+2)*64 + (g)*16 + lc], gsrc_[(row0+3)*64 + (g)*16 + lc]); \
    aw_[2] = pack2bf(gsrc_[(row0+4)*64 + (g)*16 + lc], gsrc_[(row0+5)*64 + (g)*16 + lc]); \
    aw_[3] = pack2bf(gsrc_[(row0+6)*64 + (g)*16 + lc], gsrc_[(row0+7)*64 + (g)*16 + lc]); \
    (A) = __builtin_bit_cast(short8, aw_);                                                \
    (C)[0] = (bias_)[(g)*16 + u0 + 0]; (C)[1] = (bias_)[(g)*16 + u0 + 1];                 \
    (C)[2] = (bias_)[(g)*16 + u0 + 2]; (C)[3] = (bias_)[(g)*16 + u0 + 3];                 \
  }

  // encoder gate A-frags, all 4 gates on this wave
  short8 eA0, eA1, eA2, eA3; floatx4 eC0, eC1, eC2, eC3;
  LOAD_GATE_FRAG(eA0, eC0, eWi, eWh, eb, 0);
  LOAD_GATE_FRAG(eA1, eC1, eWi, eWh, eb, 1);
  LOAD_GATE_FRAG(eA2, eC2, eWi, eWh, eb, 2);
  LOAD_GATE_FRAG(eA3, eC3, eWi, eWh, eb, 3);

  #define LSTM_EW(r, hv) {                                                            \
    float ig = sigmf(dI[r]), fg = sigmf(dF[r]), gv = tanhx(dG[r]), og = sigmf(dO[r]); \
    c4[r] = fg*c4[r] + ig*gv;                                                         \
    hv = og * tanhx(c4[r]);                                                           \
  }

  // h fragment (B-operand rows (lq&1)*8..+8 of agent lc), carried across steps.
  uintx4 hf; hf[0]=0; hf[1]=0; hf[2]=0; hf[3]=0;

  // ---- encoder: 8 LSTM steps, zero barriers, zero LDS (regs + shfl only) ----
  floatx4 c4 = {0.0f, 0.0f, 0.0f, 0.0f};
  const float2* xr2 = (const float2*)traj_rel;
  for (int t = 0; t < OBS_; ++t) {
    float2 x = xr2[t*B_ + s*N_ + lc];
    float e0 = fmaxf(fmaf(x.y, ew1[0], fmaf(x.x, ew0[0], ebv[0])), 0.0f);
    float e1 = fmaxf(fmaf(x.y, ew1[1], fmaf(x.x, ew0[1], ebv[1])), 0.0f);
    float e2 = fmaxf(fmaf(x.y, ew1[2], fmaf(x.x, ew0[2], ebv[2])), 0.0f);
    float e3 = fmaxf(fmaf(x.y, ew1[3], fmaf(x.x, ew0[3], ebv[3])), 0.0f);
    uint2 ep; ep.x = pack2bf(e0, e1); ep.y = pack2bf(e2, e3);
    uintx4 eu;
    eu[0] = shflu(ep.x, esrc0); eu[1] = shflu(ep.y, esrc0);
    eu[2] = shflu(ep.x, esrc1); eu[3] = shflu(ep.y, esrc1);
    uintx4 bu = (lq < 2) ? eu : hf;     // hi lanes: h of PREVIOUS step
    short8 bfr = __builtin_bit_cast(short8, bu);
    floatx4 dI = __builtin_amdgcn_mfma_f32_16x16x32_bf16(eA0, bfr, eC0, 0, 0, 0);
    floatx4 dF = __builtin_amdgcn_mfma_f32_16x16x32_bf16(eA1, bfr, eC1, 0, 0, 0);
    floatx4 dG = __builtin_amdgcn_mfma_f32_16x16x32_bf16(eA2, bfr, eC2, 0, 0, 0);
    floatx4 dO = __builtin_amdgcn_mfma_f32_16x16x32_bf16(eA3, bfr, eC3, 0, 0, 0);
    float h40, h41, h42, h43;
    LSTM_EW(0, h40); LSTM_EW(1, h41); LSTM_EW(2, h42); LSTM_EW(3, h43);
    uint2 hp2; hp2.x = pack2bf(h40, h41); hp2.y = pack2bf(h42, h43);
    hf[0] = shflu(hp2.x, esrc0); hf[1] = shflu(hp2.y, esrc0);
    hf[2] = shflu(hp2.x, esrc1); hf[3] = shflu(hp2.y, esrc1);
  }

  // decoder gate A-frags (separate live range from encoder's)
  short8 dA0, dA1, dA2, dA3; floatx4 dC0, dC1, dC2, dC3;
  LOAD_GATE_FRAG(dA0, dC0, dWi, dWh, db, 0);
  LOAD_GATE_FRAG(dA1, dC1, dWi, dWh, db, 1);
  LOAD_GATE_FRAG(dA2, dC2, dWi, dWh, db, 2);
  LOAD_GATE_FRAG(dA3, dC3, dWi, dWh, db, 3);

  // dec-in A-fragment: kk 0..15 = ctx rows, 16,17 = prev rows, 18..31 zero-pad
  short8 diA; floatx4 diC;
  {
    uintx4 aw; aw[0]=0; aw[1]=0; aw[2]=0; aw[3]=0;
    if (lq < 2) {
      const int r0 = lq*8;
      #pragma unroll
      for (int p = 0; p < 4; ++p)
        aw[p] = pack2bf(diW[(r0+2*p)*16 + lc], diW[(r0+2*p+1)*16 + lc]);
    } else if (lq == 2) {
      aw[0] = pack2bf(diW[16*16 + lc], diW[17*16 + lc]);
    }
    diA = __builtin_bit_cast(short8, aw);
    #pragma unroll
    for (int r = 0; r < 4; ++r) diC[r] = dib[u0 + r];
  }

  // pool C-operands, all 16 target agents, mask baked (time-invariant).
  floatx4 cm[16];
  #pragma unroll
  for (int tt = 0; tt < 16; ++tt) {
    const unsigned mi = sm_s[w][tt];
    #pragma unroll
    for (int r = 0; r < 4; ++r)
      cm[tt][r] = ((mi >> (u0 + r)) & 1u) ? bm : -1e9f;
  }

  // refrag: lanes<32 re(2pp), lanes>=32 re(2pp+1); F1 routed down via proven
  // shfl_xor(32). R24: inner loop in PACKED f32 (v_pk_fma/v_pk_max) — per-
  // element rounding identical to scalar -> bit-exact; same pack pairing.
  #define MK_REFRAG(pp, F0, F1) {                                           \
    const int t0_ = 2*(pp), t1_ = 2*(pp)+1;                                 \
    float rx0_ = PXs[t0_] - POSX, ry0_ = PYs[t0_] - POSY;                   \
    float rx1_ = PXs[t1_] - POSX, ry1_ = PYs[t1_] - POSY;                   \
    float rx_ = hi_half ? rx1_ : rx0_;                                      \
    float ry_ = hi_half ? ry1_ : ry0_;                                      \
    MK_RR_BODY(F0)                                                          \
    (F1)[0] = shflxu((F0)[0], 32);                                          \
    (F1)[1] = shflxu((F0)[1], 32);                                          \
    (F1)[2] = shflxu((F0)[2], 32);                                          \
    (F1)[3] = shflxu((F0)[3], 32);                                          \
  }

#if HAVE_PK
  #define MK_RR_BODY(F0) {                                                  \
    const floatx2 rx2_ = {rx_, rx_}, ry2_ = {ry_, ry_};                     \
    const floatx2 z2_ = {0.0f, 0.0f};                                       \
    floatx2 q0_ = MAX2(FMA2(ry2_, pWy2[0], FMA2(rx2_, pWx2[0], pB2[0])), z2_); \
    floatx2 q1_ = MAX2(FMA2(ry2_, pWy2[1], FMA2(rx2_, pWx2[1], pB2[1])), z2_); \
    floatx2 q2_ = MAX2(FMA2(ry2_, pWy2[2], FMA2(rx2_, pWx2[2], pB2[2])), z2_); \
    floatx2 q3_ = MAX2(FMA2(ry2_, pWy2[3], FMA2(rx2_, pWx2[3], pB2[3])), z2_); \
    (F0)[0] = pack2bf(q0_.x, q0_.y);                                        \
    (F0)[1] = pack2bf(q1_.x, q1_.y);                                        \
    (F0)[2] = pack2bf(q2_.x, q2_.y);                                        \
    (F0)[3] = pack2bf(q3_.x, q3_.y);                                        \
  }
#else
  #define MK_RR_BODY(F0) {                                                  \
    float rr_[8];                                                           \
    _Pragma("unroll")                                                       \
    for (int j = 0; j < 8; ++j)                                             \
      rr_[j] = fmaxf(fmaf(ry_, pWy[j], fmaf(rx_, pWx[j], pB[j])), 0.0f);    \
    (F0)[0] = pack2bf(rr_[0], rr_[1]);                                      \
    (F0)[1] = pack2bf(rr_[2], rr_[3]);                                      \
    (F0)[2] = pack2bf(rr_[4], rr_[5]);                                      \
    (F0)[3] = pack2bf(rr_[6], rr_[7]);                                      \
  }
#endif

  // pool tile; R24: nested fmaxf chain -> v_max3_f32 + max (associative,
  // bit-exact). Writer lq == tt&3 as before.
  #define POOL_TILE(tt, FRAG) {                                             \
    short8 a_ = hi_half ? __builtin_bit_cast(short8, hf)                    \
                        : __builtin_bit_cast(short8, FRAG);                 \
    floatx4 d_ = __builtin_amdgcn_mfma_f32_16x16x32_bf16(a_, bfrag, cm[tt], 0, 0, 0); \
    float pm_ = fmaxf(fmaxf(fmaxf(d_[0], d_[1]), d_[2]), d_[3]);            \
    pm_ = fmaxf(pm_, __shfl_xor(pm_, 16, 64));                              \
    pm_ = fmaxf(pm_, __shfl_xor(pm_, 32, 64));                              \
    if (lq == ((tt) & 3)) {                                                 \
      ctx_bf[w][(tt)*24 + lc] = f2bf1(fmaxf(pm_, 0.0f));                    \
    }                                                                       \
  }

  // ---- decoder: 12 autoregressive steps, ZERO barriers ----
  c4 = (floatx4){0.0f, 0.0f, 0.0f, 0.0f};
  const int MU_OFF = PRED_*B_*2;
  const int SD_OFF = 2*PRED_*B_*2;
  const float2* nz2p = (const float2*)noise;
  // prologue ctx load (step-0 ctx = zeros, written above by THIS wave)
  short8 cvN = *(const short8*)&ctx_bf[w][lc*24 + (lq&1)*8];
  for (int t = 0; t < PRED_; ++t) {
    // early noise load (float2; consumed in phase 5 by lq==0 lanes)
    const float2 nz2 = nz2p[t*B_ + s*N_ + lc];
    // phase 0: all-agent pos snapshot -> uniform regs (32 v_readlane)
    float PXs[16], PYs[16];
    #pragma unroll
    for (int a2 = 0; a2 < 16; ++a2) {
      PXs[a2] = rlanef(POSX, a2);
      PYs[a2] = rlanef(POSY, a2);
    }
    // pair-0 re fragments hoisted: their shuffles overlap phases 1-2
    uintx4 g0, g1;
    MK_REFRAG(0, g0, g1);
    // phase 1: e = relu([ctx|prev] @ dec_in_W + b) via MFMA (ctx from cvN)
    uint2 ep;
    {
      uintx4 pz; pz[0] = prevu; pz[1]=0; pz[2]=0; pz[3]=0;
      short8 pv = __builtin_bit_cast(short8, pz);
      short8 zz = {0,0,0,0,0,0,0,0};
      short8 bf1 = (lq < 2) ? cvN : ((lq == 2) ? pv : zz);
      __builtin_amdgcn_s_setprio(1);
      floatx4 d = __builtin_amdgcn_mfma_f32_16x16x32_bf16(diA, bf1, diC, 0, 0, 0);
      __builtin_amdgcn_s_setprio(0);
      ep.x = pack2bf(fmaxf(d[0],0.0f), fmaxf(d[1],0.0f));
      ep.y = pack2bf(fmaxf(d[2],0.0f), fmaxf(d[3],0.0f));
    }
    // phase 2: e fragment via 4 shfl; 4 gate MFMAs + elementwise; h -> hf only
    {
      uintx4 eu;
      eu[0] = shflu(ep.x, esrc0); eu[1] = shflu(ep.y, esrc0);
      eu[2] = shflu(ep.x, esrc1); eu[3] = shflu(ep.y, esrc1);
      uintx4 bu = (lq < 2) ? eu : hf;   // hi lanes: h of PREVIOUS step
      short8 bfr = __builtin_bit_cast(short8, bu);
      __builtin_amdgcn_s_setprio(1);
      floatx4 dI = __builtin_amdgcn_mfma_f32_16x16x32_bf16(dA0, bfr, dC0, 0, 0, 0);
      floatx4 dF = __builtin_amdgcn_mfma_f32_16x16x32_bf16(dA1, bfr, dC1, 0, 0, 0);
      floatx4 dG = __builtin_amdgcn_mfma_f32_16x16x32_bf16(dA2, bfr, dC2, 0, 0, 0);
      floatx4 dO = __builtin_amdgcn_mfma_f32_16x16x32_bf16(dA3, bfr, dC3, 0, 0, 0);
      __builtin_amdgcn_s_setprio(0);
      float h40, h41, h42, h43;
      LSTM_EW(0, h40); LSTM_EW(1, h41); LSTM_EW(2, h42); LSTM_EW(3, h43);
      uint2 hp2; hp2.x = pack2bf(h40, h41); hp2.y = pack2bf(h42, h43);
      hf[0] = shflu(hp2.x, esrc0); hf[1] = shflu(hp2.y, esrc0);
      hf[2] = shflu(hp2.x, esrc1); hf[3] = shflu(hp2.y, esrc1);
    }
    // phase 4: masked max-pool, 8 tile-pairs, lookahead-1 pipeline
    {
      #pragma unroll
      for (int p = 0; p < 8; ++p) {
        uintx4 n0, n1;
        if (p < 7) MK_REFRAG(p+1, n0, n1);
        POOL_TILE(2*p,     g0);
        POOL_TILE(2*p + 1, g1);
        g0 = n0; g1 = n1;
      }
    }
    // reload ctx fragment: this step's ctx (phase-5 B operand) AND next
    // step's phase-1 input (same-wave in-order LDS after pool writes)
    cvN = *(const short8*)&ctx_bf[w][lc*24 + (lq&1)*8];
    // phase 5: o4 via ONE MFMA (R23). Lane (0,lc): {mu_x,mu_y,scale_x,scale_y}.
    {
      uintx4 bu = (lq < 2) ? __builtin_bit_cast(uintx4, cvN) : hf;
      short8 bfr = __builtin_bit_cast(short8, bu);
      floatx4 d = __builtin_amdgcn_mfma_f32_16x16x32_bf16(oA, bfr, oC, 0, 0, 0);
      float mux = d[0], muy = d[1];
      float scx = fminf(fmaxf(d[2], -9.0f), 4.0f);
      float scy = fminf(fmaxf(d[3], -9.0f), 4.0f);
      float sdx = __expf(scx);
      float sdy = __expf(scy);
      float prxv = fmaf(sdx, nz2.x, mux);
      float pryv = fmaf(sdy, nz2.y, muy);
      if (lq == 0) {
        int o = (t*B_ + s*N_ + lc)*2;
        float2 v0; v0.x = prxv; v0.y = pryv;
        float2 v1; v1.x = mux;  v1.y = muy;
        float2 v2; v2.x = sdx;  v2.y = sdy;
        *(float2*)&out[o]          = v0;
        *(float2*)&out[MU_OFF + o] = v1;
        *(float2*)&out[SD_OFF + o] = v2;
      }
      float prx = __shfl(prxv, lc, 64);    // agent lc's x-delta (lane (0,lc))
      float pry = __shfl(pryv, lc, 64);    // agent lc's y-delta (same lane)
      POSX += prx;
      POSY += pry;
      prevu = pack2bf(prx, pry);
    }
  }
  #undef LSTM_EW
  #undef LOAD_GATE_FRAG
  #undef MK_REFRAG
  #undef MK_RR_BODY
  #undef POOL_TILE
}

extern "C" void kernel_launch(void* const* d_in, const int* in_sizes, int n_in,
                              void* d_out, int out_size, void* d_ws, size_t ws_size,
                              hipStream_t stream) {
  (void)in_sizes; (void)n_in; (void)d_ws; (void)ws_size; (void)out_size;
  traj_ar_kernel<<<dim3(S_/SCN_), dim3(128), 0, stream>>>(
      (const float*)d_in[0],  (const float*)d_in[1],  (const int*)d_in[2],   (const float*)d_in[3],
      (const float*)d_in[4],  (const float*)d_in[5],  (const float*)d_in[6], (const float*)d_in[7],
      (const float*)d_in[8],  (const float*)d_in[9],  (const float*)d_in[10],(const float*)d_in[11],
      (const float*)d_in[12], (const float*)d_in[13], (const float*)d_in[14],(const float*)d_in[15],
      (const float*)d_in[16], (const float*)d_in[17], (const float*)d_in[18],(const float*)d_in[19],
      (float*)d_out);
}